// Round 7
// baseline (275.459 us; speedup 1.0000x reference)
//
#include <hip/hip_runtime.h>
#include <hip/hip_fp16.h>
#include <type_traits>

#define NBUCK 512  // dst-range buckets; R = ceil(N/NBUCK) must be <= 256

typedef _Float16 half8 __attribute__((ext_vector_type(8)));
typedef float floatx4 __attribute__((ext_vector_type(4)));

__device__ inline void unpack8(const float4& raw, float* f) {
    const __half2* p = (const __half2*)&raw;
#pragma unroll
    for (int i = 0; i < 4; ++i) {
        float2 t = __half22float2(p[i]);
        f[2 * i] = t.x;
        f[2 * i + 1] = t.y;
    }
}

// ---------------- bucket histogram (LDS-aggregated) ----------------

__global__ void bucket_hist_kernel(const int* __restrict__ dst, int* __restrict__ bucketCnt,
                                   int E, int R) {
    __shared__ int h[NBUCK];
    int tid = threadIdx.x;
    for (int i = tid; i < NBUCK; i += blockDim.x) h[i] = 0;
    __syncthreads();
    for (int i = blockIdx.x * blockDim.x + tid; i < E; i += gridDim.x * blockDim.x)
        atomicAdd(&h[dst[i] / R], 1);
    __syncthreads();
    for (int i = tid; i < NBUCK; i += blockDim.x)
        if (h[i]) atomicAdd(&bucketCnt[i], h[i]);
}

// ---------------- scan of 512 bucket counts (single block) ----------------

__global__ void bucket_scan_kernel(const int* __restrict__ bucketCnt, int* __restrict__ bucketBase,
                                   int* __restrict__ bucketCursor) {
    __shared__ int lds[NBUCK];
    int tid = threadIdx.x;
    int v = bucketCnt[tid];
    lds[tid] = v;
    __syncthreads();
    for (int off = 1; off < NBUCK; off <<= 1) {
        int x = (tid >= off) ? lds[tid - off] : 0;
        __syncthreads();
        lds[tid] += x;
        __syncthreads();
    }
    int excl = lds[tid] - v;
    bucketBase[tid] = excl;
    bucketCursor[tid] = excl;
    if (tid == NBUCK - 1) bucketBase[NBUCK] = lds[tid];
}

// ---------------- partition edges into bucket regions ----------------

__global__ __launch_bounds__(1024) void partition_kernel(const int* __restrict__ src,
                                                         const int* __restrict__ dst,
                                                         int* __restrict__ bucketCursor,
                                                         unsigned long long* __restrict__ pairs,
                                                         int E, int R) {
    __shared__ int h[NBUCK];
    __shared__ int base[NBUCK];
    __shared__ int lcur[NBUCK];
    const int CH = 16384;
    int start = blockIdx.x * CH;
    int count = E - start;
    if (count > CH) count = CH;
    int tid = threadIdx.x;
    if (tid < NBUCK) h[tid] = 0;
    __syncthreads();
    for (int i = tid; i < count; i += 1024)
        atomicAdd(&h[dst[start + i] / R], 1);
    __syncthreads();
    if (tid < NBUCK) {
        base[tid] = h[tid] ? atomicAdd(&bucketCursor[tid], h[tid]) : 0;
        lcur[tid] = 0;
    }
    __syncthreads();
    for (int i = tid; i < count; i += 1024) {
        int d = dst[start + i];
        int s = src[start + i];
        int b = d / R;
        int r = atomicAdd(&lcur[b], 1);
        pairs[base[b] + r] = ((unsigned long long)(unsigned)s << 32) | (unsigned)d;
    }
}

// ---------------- per-bucket CSR build ----------------

__global__ void bucket_csr_kernel(const unsigned long long* __restrict__ pairs,
                                  const int* __restrict__ bucketBase, int* __restrict__ counts,
                                  int* __restrict__ offs, float* __restrict__ dinv,
                                  int* __restrict__ ssrc, int N, int R) {
    __shared__ int h[256];
    __shared__ int loffs[256];
    __shared__ int cur[256];
    int b = blockIdx.x, tid = threadIdx.x;
    int nodeBase = b * R;
    int beg = bucketBase[b], end = bucketBase[b + 1];
    h[tid] = 0;
    __syncthreads();
    for (int i = beg + tid; i < end; i += 256) {
        int d = (int)(pairs[i] & 0xffffffffull);
        atomicAdd(&h[d - nodeBase], 1);
    }
    __syncthreads();
    int v = h[tid];
    loffs[tid] = v;
    __syncthreads();
    for (int off = 1; off < 256; off <<= 1) {
        int x = (tid >= off) ? loffs[tid - off] : 0;
        __syncthreads();
        loffs[tid] += x;
        __syncthreads();
    }
    int excl = loffs[tid] - v;
    cur[tid] = excl;
    int node = nodeBase + tid;
    if (tid < R && node < N) {
        counts[node] = v;
        offs[node] = beg + excl;
        dinv[node] = rsqrtf((float)v + 1.0f);  // +1 self-loop
    }
    __syncthreads();
    for (int i = beg + tid; i < end; i += 256) {
        unsigned long long p = pairs[i];
        int d = (int)(p & 0xffffffffull);
        int s = (int)(p >> 32);
        int r = atomicAdd(&cur[d - nodeBase], 1);
        ssrc[beg + r] = s;
    }
}

// ---------------- MFMA GEMM: X(M x 64) @ W(64 x OUTD) -> fp16, no LDS ----------------

template <int OUTD, typename TIN>
__global__ void gemm_mfma_kernel(const TIN* __restrict__ X, const float* __restrict__ W,
                                 __half* __restrict__ H, int M, int ntiles) {
    constexpr int NC = OUTD / 16;
    const int lane = threadIdx.x & 63;
    const int wid  = threadIdx.x >> 6;
    const int q    = lane >> 4;
    const int m    = lane & 15;

    half8 bfrag[2][NC];
#pragma unroll
    for (int s = 0; s < 2; ++s)
#pragma unroll
        for (int c = 0; c < NC; ++c)
#pragma unroll
            for (int j = 0; j < 8; ++j)
                bfrag[s][c][j] = (_Float16)W[(s * 32 + q * 8 + j) * OUTD + c * 16 + m];

    for (int tile = blockIdx.x * 4 + wid; tile < ntiles; tile += gridDim.x * 4) {
        int rowBase = tile * 16;
        int rowA = rowBase + m;
        if (rowA > M - 1) rowA = M - 1;

        half8 afrag[2];
        if constexpr (std::is_same<TIN, float>::value) {
            const float4* Xr = (const float4*)(X + (size_t)rowA * 64);
#pragma unroll
            for (int s = 0; s < 2; ++s) {
                float4 v0 = Xr[s * 8 + q * 2 + 0];
                float4 v1 = Xr[s * 8 + q * 2 + 1];
                afrag[s][0] = (_Float16)v0.x;
                afrag[s][1] = (_Float16)v0.y;
                afrag[s][2] = (_Float16)v0.z;
                afrag[s][3] = (_Float16)v0.w;
                afrag[s][4] = (_Float16)v1.x;
                afrag[s][5] = (_Float16)v1.y;
                afrag[s][6] = (_Float16)v1.z;
                afrag[s][7] = (_Float16)v1.w;
            }
        } else {
            const half8* Xr = (const half8*)(X + (size_t)rowA * 64);
#pragma unroll
            for (int s = 0; s < 2; ++s)
                afrag[s] = Xr[s * 4 + q];
        }

        floatx4 acc[NC];
#pragma unroll
        for (int c = 0; c < NC; ++c) acc[c] = (floatx4){0.f, 0.f, 0.f, 0.f};
#pragma unroll
        for (int s = 0; s < 2; ++s)
#pragma unroll
            for (int c = 0; c < NC; ++c)
                acc[c] = __builtin_amdgcn_mfma_f32_16x16x32_f16(afrag[s], bfrag[s][c], acc[c],
                                                                0, 0, 0);

#pragma unroll
        for (int r = 0; r < 4; ++r) {
            int row = rowBase + q * 4 + r;
            if (row < M) {
#pragma unroll
                for (int c = 0; c < NC; ++c)
                    H[(size_t)row * OUTD + c * 16 + m] = __float2half(acc[c][r]);
            }
        }
    }
}

// ---------------- agg64 fused with gemm2: wave/node, 8 edges per step ----------------
// phase1: row = relu( dinv[n]*( sum h[s]*dinv[s] + h[n]*dinv[n] ) + b1 )   (in LDS)
// phase2: h2[n][j] = sum_d row[d] * W2[d][j]   (W2 staged in LDS)

__global__ __launch_bounds__(256) void agg64_fused_kernel(
    const float4* __restrict__ hrow4, const int* __restrict__ ssrc,
    const int* __restrict__ offs, const int* __restrict__ counts,
    const float* __restrict__ dinv, const float* __restrict__ b1,
    const float* __restrict__ W2, __half* __restrict__ H2, int N) {
    __shared__ float W2s[64 * 32];
    __shared__ float rows[4][64];
    int tid = threadIdx.x;
    for (int i = tid; i < 64 * 32; i += 256) W2s[i] = W2[i];
    int wid = tid >> 6, lane = tid & 63;
    int o = lane >> 3, l = lane & 7;   // 8 edges/step, 8 lanes (16B each) per 128B row
    int node = blockIdx.x * 4 + wid;

    if (node < N) {
        int beg = offs[node], cnt = counts[node];
        float a[8];
#pragma unroll
        for (int j = 0; j < 8; ++j) a[j] = 0.f;
        for (int base = 0; base < cnt; base += 64) {
            int rem = cnt - base;
            if (rem > 64) rem = 64;
            int idx = 0;
            float dv = 0.0f;
            if (lane < rem) {
                idx = ssrc[beg + base + lane];
                dv  = dinv[idx];
            }
            for (int k = 0; k < rem; k += 8) {
                int e = k + o;                    // e <= 63; invalid lanes have dv=0 -> adds 0
                int   s  = __shfl(idx, e, 64);
                float nv = __shfl(dv, e, 64);
                float4 raw = hrow4[(size_t)s * 8 + l];
                float f[8];
                unpack8(raw, f);
#pragma unroll
                for (int j = 0; j < 8; ++j) a[j] = fmaf(f[j], nv, a[j]);
            }
        }
#pragma unroll
        for (int m = 8; m < 64; m <<= 1) {
#pragma unroll
            for (int j = 0; j < 8; ++j) a[j] += __shfl_xor(a[j], m, 64);
        }
        if (o == 0) {
            float dd = dinv[node];
            float4 sraw = hrow4[(size_t)node * 8 + l];
            float sf[8];
            unpack8(sraw, sf);
#pragma unroll
            for (int j = 0; j < 8; ++j)
                rows[wid][8 * l + j] =
                    fmaxf(dd * (a[j] + sf[j] * dd) + b1[8 * l + j], 0.0f);
        }
    }
    __syncthreads();
    if (node < N) {
        int j = lane & 31;
        float acc = 0.f;
#pragma unroll
        for (int d = 0; d < 64; ++d)
            acc = fmaf(rows[wid][d], W2s[d * 32 + j], acc);
        if (lane < 32) H2[(size_t)node * 32 + j] = __float2half(acc);
    }
}

// ---------------- agg32: wave/node, 16 edges per step -> fp32 out ----------------

__global__ __launch_bounds__(256) void agg32_kernel(
    const float4* __restrict__ hrow4, const int* __restrict__ ssrc,
    const int* __restrict__ offs, const int* __restrict__ counts,
    const float* __restrict__ dinv, const float* __restrict__ b2,
    float4* __restrict__ out4, int N) {
    int tid = threadIdx.x;
    int wid = tid >> 6, lane = tid & 63;
    int o = lane >> 2, l = lane & 3;   // 16 edges/step, 4 lanes (16B each) per 64B row
    int node = blockIdx.x * 4 + wid;
    if (node >= N) return;
    int beg = offs[node], cnt = counts[node];
    float a[8];
#pragma unroll
    for (int j = 0; j < 8; ++j) a[j] = 0.f;
    for (int base = 0; base < cnt; base += 64) {
        int rem = cnt - base;
        if (rem > 64) rem = 64;
        int idx = 0;
        float dv = 0.0f;
        if (lane < rem) {
            idx = ssrc[beg + base + lane];
            dv  = dinv[idx];
        }
        for (int k = 0; k < rem; k += 16) {
            int e = k + o;                        // e <= 63
            int   s  = __shfl(idx, e, 64);
            float nv = __shfl(dv, e, 64);
            float4 raw = hrow4[(size_t)s * 4 + l];
            float f[8];
            unpack8(raw, f);
#pragma unroll
            for (int j = 0; j < 8; ++j) a[j] = fmaf(f[j], nv, a[j]);
        }
    }
#pragma unroll
    for (int m = 4; m < 64; m <<= 1) {
#pragma unroll
        for (int j = 0; j < 8; ++j) a[j] += __shfl_xor(a[j], m, 64);
    }
    if (o == 0) {
        float dd = dinv[node];
        float4 sraw = hrow4[(size_t)node * 4 + l];
        float sf[8];
        unpack8(sraw, sf);
        float r[8];
#pragma unroll
        for (int j = 0; j < 8; ++j)
            r[j] = dd * (a[j] + sf[j] * dd) + b2[8 * l + j];
        out4[(size_t)node * 8 + 2 * l + 0] = make_float4(r[0], r[1], r[2], r[3]);
        out4[(size_t)node * 8 + 2 * l + 1] = make_float4(r[4], r[5], r[6], r[7]);
    }
}

// ---------------- launch ----------------

extern "C" void kernel_launch(void* const* d_in, const int* in_sizes, int n_in,
                              void* d_out, int out_size, void* d_ws, size_t ws_size,
                              hipStream_t stream) {
    const float* x  = (const float*)d_in[0];
    const int*   ei = (const int*)d_in[1];
    const float* W1 = (const float*)d_in[2];
    const float* b1 = (const float*)d_in[3];
    const float* W2 = (const float*)d_in[4];
    const float* b2 = (const float*)d_in[5];
    float* out = (float*)d_out;

    const int N = in_sizes[0] / 64;   // 100000
    const int E = in_sizes[1] / 2;    // 1200000
    const int* src = ei;
    const int* dst = ei + E;

    const int Npad = (N + 1023) & ~1023;      // 100352
    const int R    = (N + NBUCK - 1) / NBUCK; // 196

    // workspace layout
    unsigned long long* pairs = (unsigned long long*)d_ws;    // E
    int*   ssrc   = (int*)(pairs + E);                        // E
    int*   counts = ssrc + E;                                 // Npad
    int*   offs   = counts + Npad;                            // Npad
    float* dinv   = (float*)(offs + Npad);                    // Npad
    int*   bucketCnt    = (int*)(dinv + Npad);                // NBUCK
    int*   bucketBase   = bucketCnt + NBUCK;                  // NBUCK+1
    int*   bucketCursor = bucketBase + NBUCK + 1;             // NBUCK
    // round up to 16B alignment for float4 access to h
    size_t hoff = (size_t)(bucketCursor + NBUCK + 1 - (int*)d_ws);
    hoff = (hoff + 3) & ~(size_t)3;
    __half* h  = (__half*)((int*)d_ws + hoff);                // N*64 fp16 (16B-aligned)
    __half* h2 = h + (size_t)N * 64;                          // N*32 fp16 (16B-aligned)

    const int T = 256;

    // CSR build (bucketed, write-combining-friendly)
    hipMemsetAsync(bucketCnt, 0, NBUCK * sizeof(int), stream);
    bucket_hist_kernel<<<512, T, 0, stream>>>(dst, bucketCnt, E, R);
    bucket_scan_kernel<<<1, NBUCK, 0, stream>>>(bucketCnt, bucketBase, bucketCursor);
    partition_kernel<<<(E + 16383) / 16384, 1024, 0, stream>>>(src, dst, bucketCursor, pairs, E, R);
    bucket_csr_kernel<<<NBUCK, T, 0, stream>>>(pairs, bucketBase, counts, offs, dinv, ssrc, N, R);

    const int ntiles = (N + 15) / 16;  // 6250

    // layer 1 GEMM
    gemm_mfma_kernel<64, float><<<782, T, 0, stream>>>(x, W1, h, N, ntiles);

    // layer-1 aggregation + relu + layer-2 linear (fused)
    agg64_fused_kernel<<<(N + 3) / 4, T, 0, stream>>>((const float4*)h, ssrc, offs, counts,
                                                      dinv, b1, W2, h2, N);

    // layer-2 aggregation + bias -> out
    agg32_kernel<<<(N + 3) / 4, T, 0, stream>>>((const float4*)h2, ssrc, offs, counts, dinv, b2,
                                                (float4*)out, N);
}

// Round 8
// 240.019 us; speedup vs baseline: 1.1477x; 1.1477x over previous
//
#include <hip/hip_runtime.h>
#include <hip/hip_fp16.h>
#include <type_traits>

#define NBUCK 512  // dst-range buckets; R = ceil(N/NBUCK) must be <= 256

typedef _Float16 half8 __attribute__((ext_vector_type(8)));
typedef float floatx4 __attribute__((ext_vector_type(4)));

__device__ inline void unpack8(const float4& raw, float* f) {
    const __half2* p = (const __half2*)&raw;
#pragma unroll
    for (int i = 0; i < 4; ++i) {
        float2 t = __half22float2(p[i]);
        f[2 * i] = t.x;
        f[2 * i + 1] = t.y;
    }
}

// ---------------- bucket histogram (LDS-aggregated) ----------------

__global__ void bucket_hist_kernel(const int* __restrict__ dst, int* __restrict__ bucketCnt,
                                   int E, int R) {
    __shared__ int h[NBUCK];
    int tid = threadIdx.x;
    for (int i = tid; i < NBUCK; i += blockDim.x) h[i] = 0;
    __syncthreads();
    for (int i = blockIdx.x * blockDim.x + tid; i < E; i += gridDim.x * blockDim.x)
        atomicAdd(&h[dst[i] / R], 1);
    __syncthreads();
    for (int i = tid; i < NBUCK; i += blockDim.x)
        if (h[i]) atomicAdd(&bucketCnt[i], h[i]);
}

// ---------------- scan of 512 bucket counts (single block) ----------------

__global__ void bucket_scan_kernel(const int* __restrict__ bucketCnt, int* __restrict__ bucketBase,
                                   int* __restrict__ bucketCursor) {
    __shared__ int lds[NBUCK];
    int tid = threadIdx.x;
    int v = bucketCnt[tid];
    lds[tid] = v;
    __syncthreads();
    for (int off = 1; off < NBUCK; off <<= 1) {
        int x = (tid >= off) ? lds[tid - off] : 0;
        __syncthreads();
        lds[tid] += x;
        __syncthreads();
    }
    int excl = lds[tid] - v;
    bucketBase[tid] = excl;
    bucketCursor[tid] = excl;
    if (tid == NBUCK - 1) bucketBase[NBUCK] = lds[tid];
}

// ---------------- partition edges into bucket regions ----------------

__global__ __launch_bounds__(1024) void partition_kernel(const int* __restrict__ src,
                                                         const int* __restrict__ dst,
                                                         int* __restrict__ bucketCursor,
                                                         unsigned long long* __restrict__ pairs,
                                                         int E, int R) {
    __shared__ int h[NBUCK];
    __shared__ int base[NBUCK];
    __shared__ int lcur[NBUCK];
    const int CH = 16384;
    int start = blockIdx.x * CH;
    int count = E - start;
    if (count > CH) count = CH;
    int tid = threadIdx.x;
    if (tid < NBUCK) h[tid] = 0;
    __syncthreads();
    for (int i = tid; i < count; i += 1024)
        atomicAdd(&h[dst[start + i] / R], 1);
    __syncthreads();
    if (tid < NBUCK) {
        base[tid] = h[tid] ? atomicAdd(&bucketCursor[tid], h[tid]) : 0;
        lcur[tid] = 0;
    }
    __syncthreads();
    for (int i = tid; i < count; i += 1024) {
        int d = dst[start + i];
        int s = src[start + i];
        int b = d / R;
        int r = atomicAdd(&lcur[b], 1);
        pairs[base[b] + r] = ((unsigned long long)(unsigned)s << 32) | (unsigned)d;
    }
}

// ---------------- per-bucket CSR build ----------------

__global__ void bucket_csr_kernel(const unsigned long long* __restrict__ pairs,
                                  const int* __restrict__ bucketBase, int* __restrict__ counts,
                                  int* __restrict__ offs, float* __restrict__ dinv,
                                  int* __restrict__ ssrc, int N, int R) {
    __shared__ int h[256];
    __shared__ int loffs[256];
    __shared__ int cur[256];
    int b = blockIdx.x, tid = threadIdx.x;
    int nodeBase = b * R;
    int beg = bucketBase[b], end = bucketBase[b + 1];
    h[tid] = 0;
    __syncthreads();
    for (int i = beg + tid; i < end; i += 256) {
        int d = (int)(pairs[i] & 0xffffffffull);
        atomicAdd(&h[d - nodeBase], 1);
    }
    __syncthreads();
    int v = h[tid];
    loffs[tid] = v;
    __syncthreads();
    for (int off = 1; off < 256; off <<= 1) {
        int x = (tid >= off) ? loffs[tid - off] : 0;
        __syncthreads();
        loffs[tid] += x;
        __syncthreads();
    }
    int excl = loffs[tid] - v;
    cur[tid] = excl;
    int node = nodeBase + tid;
    if (tid < R && node < N) {
        counts[node] = v;
        offs[node] = beg + excl;
        dinv[node] = rsqrtf((float)v + 1.0f);  // +1 self-loop
    }
    __syncthreads();
    for (int i = beg + tid; i < end; i += 256) {
        unsigned long long p = pairs[i];
        int d = (int)(p & 0xffffffffull);
        int s = (int)(p >> 32);
        int r = atomicAdd(&cur[d - nodeBase], 1);
        ssrc[beg + r] = s;
    }
}

// ---------------- MFMA GEMM: X(M x 64) @ W(64 x OUTD) -> fp16, no LDS ----------------

template <int OUTD, typename TIN>
__global__ void gemm_mfma_kernel(const TIN* __restrict__ X, const float* __restrict__ W,
                                 __half* __restrict__ H, int M, int ntiles) {
    constexpr int NC = OUTD / 16;
    const int lane = threadIdx.x & 63;
    const int wid  = threadIdx.x >> 6;
    const int q    = lane >> 4;
    const int m    = lane & 15;

    half8 bfrag[2][NC];
#pragma unroll
    for (int s = 0; s < 2; ++s)
#pragma unroll
        for (int c = 0; c < NC; ++c)
#pragma unroll
            for (int j = 0; j < 8; ++j)
                bfrag[s][c][j] = (_Float16)W[(s * 32 + q * 8 + j) * OUTD + c * 16 + m];

    for (int tile = blockIdx.x * 4 + wid; tile < ntiles; tile += gridDim.x * 4) {
        int rowBase = tile * 16;
        int rowA = rowBase + m;
        if (rowA > M - 1) rowA = M - 1;

        half8 afrag[2];
        if constexpr (std::is_same<TIN, float>::value) {
            const float4* Xr = (const float4*)(X + (size_t)rowA * 64);
#pragma unroll
            for (int s = 0; s < 2; ++s) {
                float4 v0 = Xr[s * 8 + q * 2 + 0];
                float4 v1 = Xr[s * 8 + q * 2 + 1];
                afrag[s][0] = (_Float16)v0.x;
                afrag[s][1] = (_Float16)v0.y;
                afrag[s][2] = (_Float16)v0.z;
                afrag[s][3] = (_Float16)v0.w;
                afrag[s][4] = (_Float16)v1.x;
                afrag[s][5] = (_Float16)v1.y;
                afrag[s][6] = (_Float16)v1.z;
                afrag[s][7] = (_Float16)v1.w;
            }
        } else {
            const half8* Xr = (const half8*)(X + (size_t)rowA * 64);
#pragma unroll
            for (int s = 0; s < 2; ++s)
                afrag[s] = Xr[s * 4 + q];
        }

        floatx4 acc[NC];
#pragma unroll
        for (int c = 0; c < NC; ++c) acc[c] = (floatx4){0.f, 0.f, 0.f, 0.f};
#pragma unroll
        for (int s = 0; s < 2; ++s)
#pragma unroll
            for (int c = 0; c < NC; ++c)
                acc[c] = __builtin_amdgcn_mfma_f32_16x16x32_f16(afrag[s], bfrag[s][c], acc[c],
                                                                0, 0, 0);

#pragma unroll
        for (int r = 0; r < 4; ++r) {
            int row = rowBase + q * 4 + r;
            if (row < M) {
#pragma unroll
                for (int c = 0; c < NC; ++c)
                    H[(size_t)row * OUTD + c * 16 + m] = __float2half(acc[c][r]);
            }
        }
    }
}

// ---------------- agg64: wave/node, float4 gathers, 2 independent loads/iter ----------------
// out1[n][:] = relu( dinv[n]*( sum h[s]*dinv[s] + h[n]*dinv[n] ) + b1 )  -> fp16 (float4 store)

__global__ __launch_bounds__(256) void agg64_kernel(
    const float4* __restrict__ hrow4, const int* __restrict__ ssrc,
    const int* __restrict__ offs, const int* __restrict__ counts,
    const float* __restrict__ dinv, const float* __restrict__ b1,
    float4* __restrict__ out4, int N) {
    int tid = threadIdx.x;
    int wid = tid >> 6, lane = tid & 63;
    int o = lane >> 3, l = lane & 7;   // 8 edge-slots, 8 lanes (16B) per 128B row
    int node = blockIdx.x * 4 + wid;
    if (node >= N) return;
    int beg = offs[node], cnt = counts[node];
    float a[8];
#pragma unroll
    for (int j = 0; j < 8; ++j) a[j] = 0.f;
    for (int base = 0; base < cnt; base += 64) {
        int rem = cnt - base;
        if (rem > 64) rem = 64;
        int idx = 0;
        float dv = 0.0f;
        if (lane < rem) {
            idx = ssrc[beg + base + lane];
            dv  = dinv[idx];
        }
        for (int k = 0; k < rem; k += 16) {
            int e0 = k + o;          // <= 63; invalid slots have dv=0 -> contribute 0
            int e1 = k + 8 + o;      // <= 63
            int   s0  = __shfl(idx, e0, 64);
            float nv0 = __shfl(dv, e0, 64);
            int   s1  = __shfl(idx, e1, 64);
            float nv1 = __shfl(dv, e1, 64);
            float4 r0 = hrow4[(size_t)s0 * 8 + l];
            float4 r1 = hrow4[(size_t)s1 * 8 + l];
            float f0[8], f1[8];
            unpack8(r0, f0);
            unpack8(r1, f1);
#pragma unroll
            for (int j = 0; j < 8; ++j) a[j] = fmaf(f0[j], nv0, a[j]);
#pragma unroll
            for (int j = 0; j < 8; ++j) a[j] = fmaf(f1[j], nv1, a[j]);
        }
    }
#pragma unroll
    for (int m = 8; m < 64; m <<= 1) {
#pragma unroll
        for (int j = 0; j < 8; ++j) a[j] += __shfl_xor(a[j], m, 64);
    }
    if (o == 0) {
        float dd = dinv[node];
        float4 sraw = hrow4[(size_t)node * 8 + l];
        float sf[8];
        unpack8(sraw, sf);
        __half2 p[4];
#pragma unroll
        for (int i = 0; i < 4; ++i) {
            float rx = fmaxf(dd * (a[2 * i] + sf[2 * i] * dd) + b1[8 * l + 2 * i], 0.0f);
            float ry = fmaxf(dd * (a[2 * i + 1] + sf[2 * i + 1] * dd) + b1[8 * l + 2 * i + 1], 0.0f);
            p[i] = __floats2half2_rn(rx, ry);
        }
        out4[(size_t)node * 8 + l] = *(const float4*)p;
    }
}

// ---------------- agg32: wave/node, 16 edges per step -> fp32 out ----------------

__global__ __launch_bounds__(256) void agg32_kernel(
    const float4* __restrict__ hrow4, const int* __restrict__ ssrc,
    const int* __restrict__ offs, const int* __restrict__ counts,
    const float* __restrict__ dinv, const float* __restrict__ b2,
    float4* __restrict__ out4, int N) {
    int tid = threadIdx.x;
    int wid = tid >> 6, lane = tid & 63;
    int o = lane >> 2, l = lane & 3;   // 16 edge-slots, 4 lanes (16B) per 64B row
    int node = blockIdx.x * 4 + wid;
    if (node >= N) return;
    int beg = offs[node], cnt = counts[node];
    float a[8];
#pragma unroll
    for (int j = 0; j < 8; ++j) a[j] = 0.f;
    for (int base = 0; base < cnt; base += 64) {
        int rem = cnt - base;
        if (rem > 64) rem = 64;
        int idx = 0;
        float dv = 0.0f;
        if (lane < rem) {
            idx = ssrc[beg + base + lane];
            dv  = dinv[idx];
        }
        for (int k = 0; k < rem; k += 16) {
            int e = k + o;                        // e <= 63
            int   s  = __shfl(idx, e, 64);
            float nv = __shfl(dv, e, 64);
            float4 raw = hrow4[(size_t)s * 4 + l];
            float f[8];
            unpack8(raw, f);
#pragma unroll
            for (int j = 0; j < 8; ++j) a[j] = fmaf(f[j], nv, a[j]);
        }
    }
#pragma unroll
    for (int m = 4; m < 64; m <<= 1) {
#pragma unroll
        for (int j = 0; j < 8; ++j) a[j] += __shfl_xor(a[j], m, 64);
    }
    if (o == 0) {
        float dd = dinv[node];
        float4 sraw = hrow4[(size_t)node * 4 + l];
        float sf[8];
        unpack8(sraw, sf);
        float r[8];
#pragma unroll
        for (int j = 0; j < 8; ++j)
            r[j] = dd * (a[j] + sf[j] * dd) + b2[8 * l + j];
        out4[(size_t)node * 8 + 2 * l + 0] = make_float4(r[0], r[1], r[2], r[3]);
        out4[(size_t)node * 8 + 2 * l + 1] = make_float4(r[4], r[5], r[6], r[7]);
    }
}

// ---------------- launch ----------------

extern "C" void kernel_launch(void* const* d_in, const int* in_sizes, int n_in,
                              void* d_out, int out_size, void* d_ws, size_t ws_size,
                              hipStream_t stream) {
    const float* x  = (const float*)d_in[0];
    const int*   ei = (const int*)d_in[1];
    const float* W1 = (const float*)d_in[2];
    const float* b1 = (const float*)d_in[3];
    const float* W2 = (const float*)d_in[4];
    const float* b2 = (const float*)d_in[5];
    float* out = (float*)d_out;

    const int N = in_sizes[0] / 64;   // 100000
    const int E = in_sizes[1] / 2;    // 1200000
    const int* src = ei;
    const int* dst = ei + E;

    const int Npad = (N + 1023) & ~1023;      // 100352
    const int R    = (N + NBUCK - 1) / NBUCK; // 196

    // workspace layout
    unsigned long long* pairs = (unsigned long long*)d_ws;    // E
    int*   ssrc   = (int*)(pairs + E);                        // E
    int*   counts = ssrc + E;                                 // Npad
    int*   offs   = counts + Npad;                            // Npad
    float* dinv   = (float*)(offs + Npad);                    // Npad
    int*   bucketCnt    = (int*)(dinv + Npad);                // NBUCK
    int*   bucketBase   = bucketCnt + NBUCK;                  // NBUCK+1
    int*   bucketCursor = bucketBase + NBUCK + 1;             // NBUCK
    // 16B alignment for float4 access to h
    size_t hoff = (size_t)(bucketCursor + NBUCK + 1 - (int*)d_ws);
    hoff = (hoff + 3) & ~(size_t)3;
    __half* h    = (__half*)((int*)d_ws + hoff);              // N*64 fp16 (16B-aligned)
    __half* out1 = h + (size_t)N * 64;                        // N*64 fp16
    __half* h2   = h;                                         // N*32 fp16, reuses h buffer

    const int T = 256;

    // CSR build (bucketed, write-combining-friendly)
    hipMemsetAsync(bucketCnt, 0, NBUCK * sizeof(int), stream);
    bucket_hist_kernel<<<512, T, 0, stream>>>(dst, bucketCnt, E, R);
    bucket_scan_kernel<<<1, NBUCK, 0, stream>>>(bucketCnt, bucketBase, bucketCursor);
    partition_kernel<<<(E + 16383) / 16384, 1024, 0, stream>>>(src, dst, bucketCursor, pairs, E, R);
    bucket_csr_kernel<<<NBUCK, T, 0, stream>>>(pairs, bucketBase, counts, offs, dinv, ssrc, N, R);

    const int ntiles = (N + 15) / 16;  // 6250

    // layer 1
    gemm_mfma_kernel<64, float><<<782, T, 0, stream>>>(x, W1, h, N, ntiles);
    agg64_kernel<<<(N + 3) / 4, T, 0, stream>>>((const float4*)h, ssrc, offs, counts, dinv, b1,
                                                (float4*)out1, N);

    // layer 2 (h2 reuses h buffer)
    gemm_mfma_kernel<32, __half><<<782, T, 0, stream>>>(out1, W2, h2, N, ntiles);
    agg32_kernel<<<(N + 3) / 4, T, 0, stream>>>((const float4*)h2, ssrc, offs, counts, dinv, b2,
                                                (float4*)out, N);
}

// Round 9
// 220.107 us; speedup vs baseline: 1.2515x; 1.0905x over previous
//
#include <hip/hip_runtime.h>
#include <hip/hip_fp16.h>
#include <type_traits>

#define NBUCK 512  // dst-range buckets; R = ceil(N/NBUCK) must be <= 256

typedef _Float16 half8 __attribute__((ext_vector_type(8)));
typedef float floatx4 __attribute__((ext_vector_type(4)));

__device__ inline void unpack8(const float4& raw, float* f) {
    const __half2* p = (const __half2*)&raw;
#pragma unroll
    for (int i = 0; i < 4; ++i) {
        float2 t = __half22float2(p[i]);
        f[2 * i] = t.x;
        f[2 * i + 1] = t.y;
    }
}

// ---------------- bucket histogram (LDS-aggregated) ----------------

__global__ void bucket_hist_kernel(const int* __restrict__ dst, int* __restrict__ bucketCnt,
                                   int E, int R) {
    __shared__ int h[NBUCK];
    int tid = threadIdx.x;
    for (int i = tid; i < NBUCK; i += blockDim.x) h[i] = 0;
    __syncthreads();
    for (int i = blockIdx.x * blockDim.x + tid; i < E; i += gridDim.x * blockDim.x)
        atomicAdd(&h[dst[i] / R], 1);
    __syncthreads();
    for (int i = tid; i < NBUCK; i += blockDim.x)
        if (h[i]) atomicAdd(&bucketCnt[i], h[i]);
}

// ---------------- scan of 512 bucket counts (single block) ----------------

__global__ void bucket_scan_kernel(const int* __restrict__ bucketCnt, int* __restrict__ bucketBase,
                                   int* __restrict__ bucketCursor) {
    __shared__ int lds[NBUCK];
    int tid = threadIdx.x;
    int v = bucketCnt[tid];
    lds[tid] = v;
    __syncthreads();
    for (int off = 1; off < NBUCK; off <<= 1) {
        int x = (tid >= off) ? lds[tid - off] : 0;
        __syncthreads();
        lds[tid] += x;
        __syncthreads();
    }
    int excl = lds[tid] - v;
    bucketBase[tid] = excl;
    bucketCursor[tid] = excl;
    if (tid == NBUCK - 1) bucketBase[NBUCK] = lds[tid];
}

// ---------------- partition edges into bucket regions ----------------

__global__ __launch_bounds__(1024) void partition_kernel(const int* __restrict__ src,
                                                         const int* __restrict__ dst,
                                                         int* __restrict__ bucketCursor,
                                                         unsigned long long* __restrict__ pairs,
                                                         int E, int R) {
    __shared__ int h[NBUCK];
    __shared__ int base[NBUCK];
    __shared__ int lcur[NBUCK];
    const int CH = 16384;
    int start = blockIdx.x * CH;
    int count = E - start;
    if (count > CH) count = CH;
    int tid = threadIdx.x;
    if (tid < NBUCK) h[tid] = 0;
    __syncthreads();
    for (int i = tid; i < count; i += 1024)
        atomicAdd(&h[dst[start + i] / R], 1);
    __syncthreads();
    if (tid < NBUCK) {
        base[tid] = h[tid] ? atomicAdd(&bucketCursor[tid], h[tid]) : 0;
        lcur[tid] = 0;
    }
    __syncthreads();
    for (int i = tid; i < count; i += 1024) {
        int d = dst[start + i];
        int s = src[start + i];
        int b = d / R;
        int r = atomicAdd(&lcur[b], 1);
        pairs[base[b] + r] = ((unsigned long long)(unsigned)s << 32) | (unsigned)d;
    }
}

// ---------------- per-bucket CSR build ----------------

__global__ void bucket_csr_kernel(const unsigned long long* __restrict__ pairs,
                                  const int* __restrict__ bucketBase, int* __restrict__ counts,
                                  int* __restrict__ offs, float* __restrict__ dinv,
                                  int* __restrict__ ssrc, int N, int R) {
    __shared__ int h[256];
    __shared__ int loffs[256];
    __shared__ int cur[256];
    int b = blockIdx.x, tid = threadIdx.x;
    int nodeBase = b * R;
    int beg = bucketBase[b], end = bucketBase[b + 1];
    h[tid] = 0;
    __syncthreads();
    for (int i = beg + tid; i < end; i += 256) {
        int d = (int)(pairs[i] & 0xffffffffull);
        atomicAdd(&h[d - nodeBase], 1);
    }
    __syncthreads();
    int v = h[tid];
    loffs[tid] = v;
    __syncthreads();
    for (int off = 1; off < 256; off <<= 1) {
        int x = (tid >= off) ? loffs[tid - off] : 0;
        __syncthreads();
        loffs[tid] += x;
        __syncthreads();
    }
    int excl = loffs[tid] - v;
    cur[tid] = excl;
    int node = nodeBase + tid;
    if (tid < R && node < N) {
        counts[node] = v;
        offs[node] = beg + excl;
        dinv[node] = rsqrtf((float)v + 1.0f);  // +1 self-loop
    }
    __syncthreads();
    for (int i = beg + tid; i < end; i += 256) {
        unsigned long long p = pairs[i];
        int d = (int)(p & 0xffffffffull);
        int s = (int)(p >> 32);
        int r = atomicAdd(&cur[d - nodeBase], 1);
        ssrc[beg + r] = s;
    }
}

// ---------------- MFMA GEMM: X(M x 64) @ W(64 x OUTD) -> fp16, no LDS ----------------

template <int OUTD, typename TIN>
__global__ void gemm_mfma_kernel(const TIN* __restrict__ X, const float* __restrict__ W,
                                 __half* __restrict__ H, int M, int ntiles) {
    constexpr int NC = OUTD / 16;
    const int lane = threadIdx.x & 63;
    const int wid  = threadIdx.x >> 6;
    const int q    = lane >> 4;
    const int m    = lane & 15;

    half8 bfrag[2][NC];
#pragma unroll
    for (int s = 0; s < 2; ++s)
#pragma unroll
        for (int c = 0; c < NC; ++c)
#pragma unroll
            for (int j = 0; j < 8; ++j)
                bfrag[s][c][j] = (_Float16)W[(s * 32 + q * 8 + j) * OUTD + c * 16 + m];

    for (int tile = blockIdx.x * 4 + wid; tile < ntiles; tile += gridDim.x * 4) {
        int rowBase = tile * 16;
        int rowA = rowBase + m;
        if (rowA > M - 1) rowA = M - 1;

        half8 afrag[2];
        if constexpr (std::is_same<TIN, float>::value) {
            const float4* Xr = (const float4*)(X + (size_t)rowA * 64);
#pragma unroll
            for (int s = 0; s < 2; ++s) {
                float4 v0 = Xr[s * 8 + q * 2 + 0];
                float4 v1 = Xr[s * 8 + q * 2 + 1];
                afrag[s][0] = (_Float16)v0.x;
                afrag[s][1] = (_Float16)v0.y;
                afrag[s][2] = (_Float16)v0.z;
                afrag[s][3] = (_Float16)v0.w;
                afrag[s][4] = (_Float16)v1.x;
                afrag[s][5] = (_Float16)v1.y;
                afrag[s][6] = (_Float16)v1.z;
                afrag[s][7] = (_Float16)v1.w;
            }
        } else {
            const half8* Xr = (const half8*)(X + (size_t)rowA * 64);
#pragma unroll
            for (int s = 0; s < 2; ++s)
                afrag[s] = Xr[s * 4 + q];
        }

        floatx4 acc[NC];
#pragma unroll
        for (int c = 0; c < NC; ++c) acc[c] = (floatx4){0.f, 0.f, 0.f, 0.f};
#pragma unroll
        for (int s = 0; s < 2; ++s)
#pragma unroll
            for (int c = 0; c < NC; ++c)
                acc[c] = __builtin_amdgcn_mfma_f32_16x16x32_f16(afrag[s], bfrag[s][c], acc[c],
                                                                0, 0, 0);

#pragma unroll
        for (int r = 0; r < 4; ++r) {
            int row = rowBase + q * 4 + r;
            if (row < M) {
#pragma unroll
                for (int c = 0; c < NC; ++c)
                    H[(size_t)row * OUTD + c * 16 + m] = __float2half(acc[c][r]);
            }
        }
    }
}

// ---------------- agg64: 8-lane group per node, no cross-lane reduction ----------------
// Each group (8 lanes x 16B) owns one node's 128B row; lane l accumulates dims 8l..8l+7.

__global__ __launch_bounds__(256) void agg64_kernel(
    const float4* __restrict__ hrow4, const int* __restrict__ ssrc,
    const int* __restrict__ offs, const int* __restrict__ counts,
    const float* __restrict__ dinv, const float* __restrict__ b1,
    float4* __restrict__ out4, int N) {
    int tid  = threadIdx.x;
    int lane = tid & 63;
    int l    = tid & 7;            // lane within group
    int gb   = lane & 56;          // group base lane within wave
    int node = blockIdx.x * 32 + (tid >> 3);
    if (node >= N) return;
    int beg = offs[node], cnt = counts[node];
    float a[8];
#pragma unroll
    for (int j = 0; j < 8; ++j) a[j] = 0.f;
    for (int base = 0; base < cnt; base += 8) {
        int p = base + l;
        int idx = 0;
        float dv = 0.0f;
        if (p < cnt) {
            idx = ssrc[beg + p];
            dv  = dinv[idx];
        }
#pragma unroll
        for (int j = 0; j < 8; ++j) {
            int   s  = __shfl(idx, gb | j, 64);
            float nv = __shfl(dv, gb | j, 64);
            float4 raw = hrow4[(size_t)s * 8 + l];
            float f[8];
            unpack8(raw, f);
#pragma unroll
            for (int d = 0; d < 8; ++d) a[d] = fmaf(f[d], nv, a[d]);
        }
    }
    float dd = dinv[node];
    float4 sraw = hrow4[(size_t)node * 8 + l];
    float sf[8];
    unpack8(sraw, sf);
    __half2 pk[4];
#pragma unroll
    for (int i = 0; i < 4; ++i) {
        float rx = fmaxf(dd * (a[2 * i] + sf[2 * i] * dd) + b1[8 * l + 2 * i], 0.0f);
        float ry = fmaxf(dd * (a[2 * i + 1] + sf[2 * i + 1] * dd) + b1[8 * l + 2 * i + 1], 0.0f);
        pk[i] = __floats2half2_rn(rx, ry);
    }
    out4[(size_t)node * 8 + l] = *(const float4*)pk;
}

// ---------------- agg32: 4-lane group per node -> fp32 out ----------------
// Each group (4 lanes x 16B) owns one node's 64B fp16 row; lane l accumulates dims 8l..8l+7.

__global__ __launch_bounds__(256) void agg32_kernel(
    const float4* __restrict__ hrow4, const int* __restrict__ ssrc,
    const int* __restrict__ offs, const int* __restrict__ counts,
    const float* __restrict__ dinv, const float* __restrict__ b2,
    float4* __restrict__ out4, int N) {
    int tid  = threadIdx.x;
    int lane = tid & 63;
    int l    = tid & 3;            // lane within group
    int gb   = lane & 60;          // group base lane within wave
    int node = blockIdx.x * 64 + (tid >> 2);
    if (node >= N) return;
    int beg = offs[node], cnt = counts[node];
    float a[8];
#pragma unroll
    for (int j = 0; j < 8; ++j) a[j] = 0.f;
    for (int base = 0; base < cnt; base += 4) {
        int p = base + l;
        int idx = 0;
        float dv = 0.0f;
        if (p < cnt) {
            idx = ssrc[beg + p];
            dv  = dinv[idx];
        }
#pragma unroll
        for (int j = 0; j < 4; ++j) {
            int   s  = __shfl(idx, gb | j, 64);
            float nv = __shfl(dv, gb | j, 64);
            float4 raw = hrow4[(size_t)s * 4 + l];
            float f[8];
            unpack8(raw, f);
#pragma unroll
            for (int d = 0; d < 8; ++d) a[d] = fmaf(f[d], nv, a[d]);
        }
    }
    float dd = dinv[node];
    float4 sraw = hrow4[(size_t)node * 4 + l];
    float sf[8];
    unpack8(sraw, sf);
    float r[8];
#pragma unroll
    for (int j = 0; j < 8; ++j)
        r[j] = dd * (a[j] + sf[j] * dd) + b2[8 * l + j];
    out4[(size_t)node * 8 + 2 * l + 0] = make_float4(r[0], r[1], r[2], r[3]);
    out4[(size_t)node * 8 + 2 * l + 1] = make_float4(r[4], r[5], r[6], r[7]);
}

// ---------------- launch ----------------

extern "C" void kernel_launch(void* const* d_in, const int* in_sizes, int n_in,
                              void* d_out, int out_size, void* d_ws, size_t ws_size,
                              hipStream_t stream) {
    const float* x  = (const float*)d_in[0];
    const int*   ei = (const int*)d_in[1];
    const float* W1 = (const float*)d_in[2];
    const float* b1 = (const float*)d_in[3];
    const float* W2 = (const float*)d_in[4];
    const float* b2 = (const float*)d_in[5];
    float* out = (float*)d_out;

    const int N = in_sizes[0] / 64;   // 100000
    const int E = in_sizes[1] / 2;    // 1200000
    const int* src = ei;
    const int* dst = ei + E;

    const int Npad = (N + 1023) & ~1023;      // 100352
    const int R    = (N + NBUCK - 1) / NBUCK; // 196

    // workspace layout
    unsigned long long* pairs = (unsigned long long*)d_ws;    // E
    int*   ssrc   = (int*)(pairs + E);                        // E
    int*   counts = ssrc + E;                                 // Npad
    int*   offs   = counts + Npad;                            // Npad
    float* dinv   = (float*)(offs + Npad);                    // Npad
    int*   bucketCnt    = (int*)(dinv + Npad);                // NBUCK
    int*   bucketBase   = bucketCnt + NBUCK;                  // NBUCK+1
    int*   bucketCursor = bucketBase + NBUCK + 1;             // NBUCK
    // 16B alignment for float4 access to h
    size_t hoff = (size_t)(bucketCursor + NBUCK + 1 - (int*)d_ws);
    hoff = (hoff + 3) & ~(size_t)3;
    __half* h    = (__half*)((int*)d_ws + hoff);              // N*64 fp16 (16B-aligned)
    __half* out1 = h + (size_t)N * 64;                        // N*64 fp16
    __half* h2   = h;                                         // N*32 fp16, reuses h buffer

    const int T = 256;

    // CSR build (bucketed, write-combining-friendly)
    hipMemsetAsync(bucketCnt, 0, NBUCK * sizeof(int), stream);
    bucket_hist_kernel<<<512, T, 0, stream>>>(dst, bucketCnt, E, R);
    bucket_scan_kernel<<<1, NBUCK, 0, stream>>>(bucketCnt, bucketBase, bucketCursor);
    partition_kernel<<<(E + 16383) / 16384, 1024, 0, stream>>>(src, dst, bucketCursor, pairs, E, R);
    bucket_csr_kernel<<<NBUCK, T, 0, stream>>>(pairs, bucketBase, counts, offs, dinv, ssrc, N, R);

    const int ntiles = (N + 15) / 16;  // 6250

    // layer 1
    gemm_mfma_kernel<64, float><<<782, T, 0, stream>>>(x, W1, h, N, ntiles);
    agg64_kernel<<<(N + 31) / 32, T, 0, stream>>>((const float4*)h, ssrc, offs, counts, dinv, b1,
                                                  (float4*)out1, N);

    // layer 2 (h2 reuses h buffer)
    gemm_mfma_kernel<32, __half><<<782, T, 0, stream>>>(out1, W2, h2, N, ntiles);
    agg32_kernel<<<(N + 63) / 64, T, 0, stream>>>((const float4*)h2, ssrc, offs, counts, dinv, b2,
                                                  (float4*)out, N);
}